// Round 13
// baseline (1041.594 us; speedup 1.0000x reference)
//
#include <hip/hip_runtime.h>

#define N_NODES 100000
#define N_EDGES 1600000
#define D 128
#define DH 256
#define N_GRAPHS 512
#define EPS 1e-5f
#define NPART 8
#define PSIZE 12500      // N_NODES / NPART
#define FCHUNK 4096      // edges per split chunk
#define PCAP 210000      // staging capacity per partition (~24 sigma)
#define SBSZ 196         // nodes per sub-bucket (64 per partition)
#define SBCAP 4608       // staging capacity per sub-bucket (~26 sigma)
#define CH2 8192         // edges per split2 block
#define DBINS 64         // degree bins for perm sort

typedef _Float16 h8 __attribute__((ext_vector_type(8)));
typedef float f4 __attribute__((ext_vector_type(4)));

// ---------------- preprocessing: fully-coalesced CSR build ----------------

__global__ __launch_bounds__(256) void k_split(const int* __restrict__ src,
                                               const int* __restrict__ dst,
                                               int* __restrict__ pcur,
                                               unsigned* __restrict__ staging) {
    int t = threadIdx.x;
    int base = blockIdx.x * FCHUNK;
    int dbuf[16], sbuf[16], pbuf[16];
#pragma unroll
    for (int j = 0; j < 16; ++j) {
        int i = base + j * 256 + t;
        bool v = i < N_EDGES;
        int d = v ? dst[i] : 0;
        dbuf[j] = d;
        sbuf[j] = v ? src[i] : 0;
        pbuf[j] = v ? d / PSIZE : 8;
    }
    int cnt_loc[8];
#pragma unroll
    for (int p = 0; p < 8; ++p) {
        int c = 0;
#pragma unroll
        for (int j = 0; j < 16; ++j) c += (pbuf[j] == p);
        cnt_loc[p] = c;
    }
    __shared__ int tmp[256][9];
#pragma unroll
    for (int p = 0; p < 8; ++p) tmp[t][p] = cnt_loc[p];
    __syncthreads();
    for (int off = 1; off < 256; off <<= 1) {
        int vals[8];
        if (t >= off) {
#pragma unroll
            for (int p = 0; p < 8; ++p) vals[p] = tmp[t - off][p];
        }
        __syncthreads();
        if (t >= off) {
#pragma unroll
            for (int p = 0; p < 8; ++p) tmp[t][p] += vals[p];
        }
        __syncthreads();
    }
    __shared__ int bbase_s[8];
    if (t < 8) bbase_s[t] = atomicAdd(&pcur[t], tmp[255][t]);
    __syncthreads();
#pragma unroll
    for (int p = 0; p < 8; ++p) {
        int off = bbase_s[p] + tmp[t][p] - cnt_loc[p];
        unsigned* sp = staging + (size_t)p * PCAP;
#pragma unroll
        for (int j = 0; j < 16; ++j) {
            if (pbuf[j] == p) {
                sp[off++] = ((unsigned)(dbuf[j] - p * PSIZE) << 17) | (unsigned)sbuf[j];
            }
        }
    }
}

__global__ __launch_bounds__(256) void k_split2(const unsigned* __restrict__ staging,
                                                const int* __restrict__ pcur,
                                                int* __restrict__ pcur2,
                                                unsigned* __restrict__ stag2) {
    int p = blockIdx.x & 7;
    int chunk = blockIdx.x >> 3;
    int total = min(pcur[p], PCAP);
    int base = chunk * CH2;
    if (base >= total) return;
    int lim = min(CH2, total - base);
    const unsigned* sp = staging + (size_t)p * PCAP + base;
    __shared__ unsigned buf[CH2];
    __shared__ int hist[64], scan[64], cur[64], gbase[64];
    int t = threadIdx.x;
    if (t < 64) hist[t] = 0;
    __syncthreads();
    for (int i = t; i < lim; i += 256) {
        unsigned pk = sp[i];
        atomicAdd(&hist[(pk >> 17) / SBSZ], 1);
    }
    __syncthreads();
    if (t < 64) {
        gbase[t] = atomicAdd(&pcur2[p * 64 + t], hist[t]);
        cur[t] = 0;
    }
    if (t == 0) {
        int acc = 0;
        for (int j = 0; j < 64; ++j) {
            scan[j] = acc;
            acc += hist[j];
        }
    }
    __syncthreads();
    for (int i = t; i < lim; i += 256) {
        unsigned pk = sp[i];
        int sb = (pk >> 17) / SBSZ;
        int r = atomicAdd(&cur[sb], 1);
        buf[scan[sb] + r] = pk;
    }
    __syncthreads();
    for (int sb = 0; sb < 64; ++sb) {
        int n = hist[sb];
        int gb = gbase[sb];
        if (gb >= SBCAP) continue;
        int nn = min(n, SBCAP - gb);
        unsigned* dstp = stag2 + ((size_t)(p * 64 + sb)) * SBCAP + gb;
        for (int i = t; i < nn; i += 256) dstp[i] = buf[scan[sb] + i];
    }
}

__global__ void k_sbscan(int* __restrict__ pcur2, int* __restrict__ sbbase,
                         int* __restrict__ offs) {
    __shared__ int tmp[512];
    int t = threadIdx.x;
    int v = min(pcur2[t], SBCAP);
    tmp[t] = v;
    __syncthreads();
    for (int off = 1; off < 512; off <<= 1) {
        int u = (t >= off) ? tmp[t - off] : 0;
        __syncthreads();
        tmp[t] += u;
        __syncthreads();
    }
    sbbase[t] = tmp[t] - v;
    if (t == 511) offs[N_NODES] = tmp[511];
}

__global__ __launch_bounds__(256) void k_sort3(const unsigned* __restrict__ stag2,
                                               const int* __restrict__ pcur2,
                                               const int* __restrict__ sbbase,
                                               int* __restrict__ offs,
                                               float* __restrict__ dinv,
                                               int* __restrict__ csr) {
    int sb = blockIdx.x;  // 0..511
    int p = sb >> 6, s = sb & 63;
    int n = min(pcur2[sb], SBCAP);
    int gb = sbbase[sb];
    int node0 = p * PSIZE + s * SBSZ;
    int nloc = min(SBSZ, PSIZE - s * SBSZ);
    __shared__ int hist[SBSZ], scan[SBSZ], cur[SBSZ];
    __shared__ int sorted[SBCAP];
    int t = threadIdx.x;
    for (int i = t; i < SBSZ; i += 256) {
        hist[i] = 0;
        cur[i] = 0;
    }
    __syncthreads();
    const unsigned* sp = stag2 + (size_t)sb * SBCAP;
    for (int i = t; i < n; i += 256)
        atomicAdd(&hist[(int)(sp[i] >> 17) - s * SBSZ], 1);
    __syncthreads();
    if (t == 0) {
        int acc = 0;
        for (int j = 0; j < SBSZ; ++j) {
            scan[j] = acc;
            acc += hist[j];
        }
    }
    __syncthreads();
    for (int i = t; i < nloc; i += 256) {
        offs[node0 + i] = gb + scan[i];
        dinv[node0 + i] = rsqrtf((float)(hist[i] + 1));
    }
    for (int i = t; i < n; i += 256) {
        unsigned pk = sp[i];
        int dl = (int)(pk >> 17) - s * SBSZ;
        int r = atomicAdd(&cur[dl], 1);
        sorted[scan[dl] + r] = (int)(pk & 0x1FFFFu);
    }
    __syncthreads();
    for (int i = t; i < n; i += 256) csr[gb + i] = sorted[i];
}

// ---------------- degree-sorted node permutation (anti-divergence) ---------

__global__ void k_deghist(const int* __restrict__ offs, int* __restrict__ dhist) {
    int n = blockIdx.x * 256 + threadIdx.x;
    if (n >= N_NODES) return;
    int deg = offs[n + 1] - offs[n];
    atomicAdd(&dhist[min(deg, DBINS - 1)], 1);
}

__global__ void k_degscan(const int* __restrict__ dhist, int* __restrict__ dbase) {
    __shared__ int tmp[DBINS];
    int t = threadIdx.x;
    int v = dhist[t];
    tmp[t] = v;
    __syncthreads();
    for (int off = 1; off < DBINS; off <<= 1) {
        int u = (t >= off) ? tmp[t - off] : 0;
        __syncthreads();
        tmp[t] += u;
        __syncthreads();
    }
    dbase[t] = tmp[t] - v;
}

__global__ void k_degfill(const int* __restrict__ offs, const int* __restrict__ dbase,
                          int* __restrict__ dcur, int* __restrict__ perm) {
    int n = blockIdx.x * 256 + threadIdx.x;
    if (n >= N_NODES) return;
    int deg = min(offs[n + 1] - offs[n], DBINS - 1);
    int pos = dbase[deg] + atomicAdd(&dcur[deg], 1);
    perm[pos] = n;
}

// BN fold merged: blocks 0..63: WT[n][k] = a[k]*W[k][n] (fp16); block 64: r[j]
__global__ void k_fold(const float* __restrict__ W, const float* __restrict__ a,
                       const float* __restrict__ c, int use_bn,
                       _Float16* __restrict__ WT, float* __restrict__ r) {
    if (blockIdx.x < 64) {
        int idx = blockIdx.x * 256 + threadIdx.x;
        int n = idx >> 7, k = idx & 127;
        float s = use_bn ? a[k] : 1.0f;
        WT[idx] = (_Float16)(s * W[k * D + n]);
    } else if (threadIdx.x < 128) {
        int j = threadIdx.x;
        float s = 0.f;
        if (use_bn)
            for (int k = 0; k < D; ++k) s = fmaf(c[k], W[k * D + j], s);
        r[j] = s;
    }
}

// ---------------- MFMA GEMM: Y'[n] = dinv[n]*(X[n]@W + r), fp16 out ---------
template <bool F32IN>
__global__ __launch_bounds__(256) void k_gemm(const void* __restrict__ Xv,
                                              const _Float16* __restrict__ WT,
                                              const float* __restrict__ radd,
                                              const float* __restrict__ dinv,
                                              _Float16* __restrict__ Y, int nrows) {
    __shared__ _Float16 Wl[128][136];
    __shared__ _Float16 Yl[64][136];
    int t = threadIdx.x;
    {
        const h8* src = (const h8*)WT;
        for (int i = t; i < 128 * 16; i += 256) {
            int r = i >> 4, c = i & 15;
            *(h8*)&Wl[r][c * 8] = src[i];
        }
    }
    int wave = t >> 6;
    int lane = t & 63;
    int l15 = lane & 15;
    int quad = lane >> 4;
    int rowblk = blockIdx.x * 64;
    int row0 = rowblk + wave * 16;

    h8 zero8;
#pragma unroll
    for (int j = 0; j < 8; ++j) zero8[j] = (_Float16)0;

    h8 a[4];
    bool inb = (row0 + l15) < nrows;
#pragma unroll
    for (int kt = 0; kt < 4; ++kt) a[kt] = zero8;
    if (inb) {
        if constexpr (F32IN) {
            const float* xrow = (const float*)Xv + (size_t)(row0 + l15) * D + quad * 8;
#pragma unroll
            for (int kt = 0; kt < 4; ++kt) {
                float4 u = *(const float4*)(xrow + kt * 32);
                float4 w = *(const float4*)(xrow + kt * 32 + 4);
                h8 o;
                o[0] = (_Float16)u.x; o[1] = (_Float16)u.y;
                o[2] = (_Float16)u.z; o[3] = (_Float16)u.w;
                o[4] = (_Float16)w.x; o[5] = (_Float16)w.y;
                o[6] = (_Float16)w.z; o[7] = (_Float16)w.w;
                a[kt] = o;
            }
        } else {
            const _Float16* xrow = (const _Float16*)Xv + (size_t)(row0 + l15) * D + quad * 8;
#pragma unroll
            for (int kt = 0; kt < 4; ++kt) a[kt] = *(const h8*)(xrow + kt * 32);
        }
    }

    __syncthreads();

    f4 acc[8];
#pragma unroll
    for (int n = 0; n < 8; ++n) {
        acc[n][0] = 0.f; acc[n][1] = 0.f; acc[n][2] = 0.f; acc[n][3] = 0.f;
#pragma unroll
        for (int kt = 0; kt < 4; ++kt) {
            h8 b = *(const h8*)&Wl[n * 16 + l15][kt * 32 + quad * 8];
            acc[n] = __builtin_amdgcn_mfma_f32_16x16x32_f16(a[kt], b, acc[n], 0, 0, 0);
        }
    }
    float dv[4];
    int rbase = rowblk + wave * 16 + quad * 4;
#pragma unroll
    for (int i = 0; i < 4; ++i)
        dv[i] = (rbase + i < nrows) ? dinv[rbase + i] : 0.f;
#pragma unroll
    for (int n = 0; n < 8; ++n) {
        float r = radd[n * 16 + l15];
#pragma unroll
        for (int i = 0; i < 4; ++i)
            Yl[wave * 16 + quad * 4 + i][n * 16 + l15] = (_Float16)((acc[n][i] + r) * dv[i]);
    }
    __syncthreads();
    for (int i = t; i < 64 * 16; i += 256) {
        int r = i >> 4, c = i & 15;
        if (rowblk + r < nrows)
            *(h8*)&Y[(size_t)(rowblk + r) * D + c * 8] = *(h8*)&Yl[r][c * 8];
    }
}

// ---------------- aggregate + relu + fused BN partial stats ----------------
// degree-sorted perm: the 16 nodes per block have ~equal degree -> no
// divergence waste in the unrolled edge loop.
__global__ __launch_bounds__(256) void k_aggregate(const h8* __restrict__ Y8,
                                                   const int* __restrict__ offs,
                                                   const int* __restrict__ csr,
                                                   const float* __restrict__ dinv,
                                                   const float* __restrict__ bias,
                                                   const int* __restrict__ perm,
                                                   h8* __restrict__ A8,
                                                   float* __restrict__ part) {
    int grp = threadIdx.x >> 4;
    int lane = threadIdx.x & 15;
    int node = perm[blockIdx.x * 16 + grp];
    int beg = offs[node], end = offs[node + 1];
    float dn = dinv[node];
    float acc[8];
    h8 y = Y8[(size_t)node * 16 + lane];
#pragma unroll
    for (int i = 0; i < 8; ++i) acc[i] = (float)y[i];
    int e = beg;
    for (; e + 7 < end; e += 8) {
        int s0 = csr[e], s1 = csr[e + 1], s2 = csr[e + 2], s3 = csr[e + 3];
        int s4 = csr[e + 4], s5 = csr[e + 5], s6 = csr[e + 6], s7 = csr[e + 7];
        h8 v0 = Y8[(size_t)s0 * 16 + lane];
        h8 v1 = Y8[(size_t)s1 * 16 + lane];
        h8 v2 = Y8[(size_t)s2 * 16 + lane];
        h8 v3 = Y8[(size_t)s3 * 16 + lane];
        h8 v4 = Y8[(size_t)s4 * 16 + lane];
        h8 v5 = Y8[(size_t)s5 * 16 + lane];
        h8 v6 = Y8[(size_t)s6 * 16 + lane];
        h8 v7 = Y8[(size_t)s7 * 16 + lane];
#pragma unroll
        for (int i = 0; i < 8; ++i) {
            acc[i] += (float)v0[i] + (float)v1[i] + (float)v2[i] + (float)v3[i];
            acc[i] += (float)v4[i] + (float)v5[i] + (float)v6[i] + (float)v7[i];
        }
    }
    if (e + 3 < end) {
        int s0 = csr[e], s1 = csr[e + 1], s2 = csr[e + 2], s3 = csr[e + 3];
        h8 v0 = Y8[(size_t)s0 * 16 + lane];
        h8 v1 = Y8[(size_t)s1 * 16 + lane];
        h8 v2 = Y8[(size_t)s2 * 16 + lane];
        h8 v3 = Y8[(size_t)s3 * 16 + lane];
#pragma unroll
        for (int i = 0; i < 8; ++i)
            acc[i] += (float)v0[i] + (float)v1[i] + (float)v2[i] + (float)v3[i];
        e += 4;
    }
    for (; e < end; ++e) {
        int s = csr[e];
        h8 v = Y8[(size_t)s * 16 + lane];
#pragma unroll
        for (int i = 0; i < 8; ++i) acc[i] += (float)v[i];
    }
    __shared__ float red[16][128];
    h8 o;
#pragma unroll
    for (int i = 0; i < 8; ++i) {
        float v = fmaxf(fmaf(acc[i], dn, bias[lane * 8 + i]), 0.f);
        o[i] = (_Float16)v;
        red[grp][lane * 8 + i] = v;
    }
    __builtin_nontemporal_store(o, &A8[(size_t)node * 16 + lane]);
    __syncthreads();
    if (threadIdx.x < 128) {
        int c = threadIdx.x;
        float s = 0.f, s2 = 0.f;
#pragma unroll
        for (int g = 0; g < 16; ++g) {
            float v = red[g][c];
            s += v;
            s2 = fmaf(v, v, s2);
        }
        float* p = part + (size_t)(blockIdx.x & 31) * 256;
        atomicAdd(&p[c], s);
        atomicAdd(&p[128 + c], s2);
    }
}

__global__ void k_bn_coeffs(float* __restrict__ part, int stripes, int stride,
                            int coff, const float* __restrict__ g,
                            const float* __restrict__ beta, float* __restrict__ a,
                            float* __restrict__ c, float inv_n) {
    int i = threadIdx.x;
    float s = 0.f, s2 = 0.f;
    for (int st = 0; st < stripes; ++st) {
        s += part[st * stride + i];
        s2 += part[st * stride + coff + i];
        part[st * stride + i] = 0.f;
        part[st * stride + coff + i] = 0.f;
    }
    float m = s * inv_n;
    float v = s2 * inv_n - m * m;
    float ai = g[i] * rsqrtf(v + EPS);
    a[i] = ai;
    c[i] = beta[i] - m * ai;
}

// ---------------- pooling + MLP head ----------------

__global__ void k_starts(const int* __restrict__ batch, int* __restrict__ starts) {
    int n = blockIdx.x * 256 + threadIdx.x;
    if (n >= N_NODES) return;
    int b = batch[n];
    int prev = (n == 0) ? -1 : batch[n - 1];
    for (int g = prev + 1; g <= b; ++g) starts[g] = n;
    if (n == N_NODES - 1)
        for (int g = b + 1; g <= N_GRAPHS; ++g) starts[g] = N_NODES;
}

__global__ __launch_bounds__(256) void k_pool(const h8* __restrict__ x8,
                                              const int* __restrict__ starts,
                                              const float* __restrict__ a,
                                              const float* __restrict__ c,
                                              float* __restrict__ pooled) {
    int g = blockIdx.x;
    int grp = threadIdx.x >> 4;
    int lane = threadIdx.x & 15;
    int beg = starts[g], end = starts[g + 1];
    float s[8] = {};
    for (int n = beg + grp; n < end; n += 16) {
        h8 v = x8[(size_t)n * 16 + lane];
#pragma unroll
        for (int i = 0; i < 8; ++i) s[i] += (float)v[i];
    }
    __shared__ float red[16][128];
#pragma unroll
    for (int i = 0; i < 8; ++i) red[grp][lane * 8 + i] = s[i];
    __syncthreads();
    if (threadIdx.x < 128) {
        int ch = threadIdx.x;
        float t = 0.f;
#pragma unroll
        for (int gg = 0; gg < 16; ++gg) t += red[gg][ch];
        float cnt = (float)(end - beg);
        pooled[g * D + ch] = fmaf(a[ch], t, cnt * c[ch]);
    }
}

template <int K>
__global__ __launch_bounds__(256) void k_dense(const float* __restrict__ in,
                                               const float* __restrict__ W,
                                               const float* __restrict__ b,
                                               float* __restrict__ out) {
    __shared__ float inl[K];
    int row = blockIdx.x;
    for (int k = threadIdx.x; k < K; k += 256) inl[k] = in[row * K + k];
    __syncthreads();
    int j = threadIdx.x;
    float acc = b[j];
#pragma unroll
    for (int k = 0; k < K; ++k) acc = fmaf(inl[k], W[k * 256 + j], acc);
    out[row * 256 + j] = fmaxf(acc, 0.0f);
}

__global__ void k_head_stats(const float* __restrict__ x, float* __restrict__ sums,
                             float* __restrict__ sumsq, int rows) {
    int c = threadIdx.x;
    float s = 0.f, s2 = 0.f;
    int r0 = blockIdx.x * 8;
    int r1 = min(r0 + 8, rows);
    for (int r = r0; r < r1; ++r) {
        float v = x[r * DH + c];
        s += v;
        s2 = fmaf(v, v, s2);
    }
    atomicAdd(&sums[c], s);
    atomicAdd(&sumsq[c], s2);
}

__global__ void k_head_apply(float* __restrict__ x, const float* __restrict__ a,
                             const float* __restrict__ c) {
    int i = blockIdx.x * 256 + threadIdx.x;
    float4 v = ((float4*)x)[i];
    int col = (i << 2) & 255;
    v.x = fmaf(v.x, a[col], c[col]);
    v.y = fmaf(v.y, a[col + 1], c[col + 1]);
    v.z = fmaf(v.z, a[col + 2], c[col + 2]);
    v.w = fmaf(v.w, a[col + 3], c[col + 3]);
    ((float4*)x)[i] = v;
}

__global__ void k_final(const float* __restrict__ h, const float* __restrict__ Wout,
                        const float* __restrict__ bout, float* __restrict__ out) {
    int g = blockIdx.x * 4 + (threadIdx.x >> 6);
    int lane = threadIdx.x & 63;
    float4 v = ((const float4*)(h + g * DH))[lane];
    float4 w = ((const float4*)Wout)[lane];
    float acc = v.x * w.x + v.y * w.y + v.z * w.z + v.w * w.w;
#pragma unroll
    for (int off = 32; off; off >>= 1) acc += __shfl_down(acc, off, 64);
    if (lane == 0) out[g] = acc + bout[0];
}

// ---------------- launch ----------------

extern "C" void kernel_launch(void* const* d_in, const int* in_sizes, int n_in,
                              void* d_out, int out_size, void* d_ws, size_t ws_size,
                              hipStream_t stream) {
    const float* x = (const float*)d_in[0];
    const int* ei = (const int*)d_in[1];
    const int* batch = (const int*)d_in[2];
    const float* Wc = (const float*)d_in[3];
    const float* bc = (const float*)d_in[4];
    const float* gc = (const float*)d_in[5];
    const float* bec = (const float*)d_in[6];
    const float* Wh0 = (const float*)d_in[7];
    const float* bh0 = (const float*)d_in[8];
    const float* gh0 = (const float*)d_in[9];
    const float* beh0 = (const float*)d_in[10];
    const float* Wh1 = (const float*)d_in[11];
    const float* bh1 = (const float*)d_in[12];
    const float* gh1 = (const float*)d_in[13];
    const float* beh1 = (const float*)d_in[14];
    const float* Wout = (const float*)d_in[15];
    const float* bout = (const float*)d_in[16];
    float* out = (float*)d_out;

    const int* src = ei;
    const int* dst = ei + N_EDGES;

    char* base = (char*)d_ws;
    size_t woff = 0;
    auto alloc = [&](size_t bytes) -> char* {
        char* p = base + woff;
        woff = (woff + bytes + 255) & ~(size_t)255;
        return p;
    };
    _Float16* bufY = (_Float16*)alloc(sizeof(_Float16) * (size_t)N_NODES * D);
    _Float16* bufA = (_Float16*)alloc(sizeof(_Float16) * (size_t)N_NODES * D);
    float* dinv = (float*)alloc(sizeof(float) * N_NODES);
    int* csr = (int*)alloc(sizeof(int) * N_EDGES);
    int* perm = (int*)alloc(sizeof(int) * N_NODES);
    unsigned* staging = (unsigned*)alloc(sizeof(unsigned) * 8 * PCAP);
    unsigned* stag2 = (unsigned*)alloc(sizeof(unsigned) * 512 * SBCAP);
    // single zeroed region: pcur(64) + pcur2(512) + dhist(64) + dcur(64) + part + stats
    size_t zero_bytes =
        sizeof(int) * (64 + 512 + 64 + 64) + sizeof(float) * (32 * 256 + 512);
    char* zero_base = alloc(zero_bytes);
    int* pcur = (int*)zero_base;
    int* pcur2 = pcur + 64;
    int* dhist = pcur2 + 512;
    int* dcur = dhist + 64;
    float* part = (float*)(dcur + 64);
    float* stats = part + 32 * 256;
    float* sums = stats;
    float* sumsq = stats + 256;
    int* offs = (int*)alloc(sizeof(int) * (N_NODES + 1));
    int* sbbase = (int*)alloc(sizeof(int) * 512);
    int* dbase = (int*)alloc(sizeof(int) * 64);
    float* avec = (float*)alloc(sizeof(float) * 256);
    float* cvec = (float*)alloc(sizeof(float) * 256);
    _Float16* WT = (_Float16*)alloc(sizeof(_Float16) * D * D);
    float* rvec = (float*)alloc(sizeof(float) * 128);
    int* starts = (int*)alloc(sizeof(int) * (N_GRAPHS + 1));
    float* pooled = (float*)alloc(sizeof(float) * N_GRAPHS * D);
    float* h0 = (float*)alloc(sizeof(float) * N_GRAPHS * DH);
    float* h1 = (float*)alloc(sizeof(float) * N_GRAPHS * DH);

    hipMemsetAsync(zero_base, 0, zero_bytes, stream);

    int nbl = (N_NODES + 255) / 256;
    int split_grid = (N_EDGES + FCHUNK - 1) / FCHUNK;
    int split2_grid = ((PCAP + CH2 - 1) / CH2) * 8;
    k_split<<<split_grid, 256, 0, stream>>>(src, dst, pcur, staging);
    k_split2<<<split2_grid, 256, 0, stream>>>(staging, pcur, pcur2, stag2);
    k_sbscan<<<1, 512, 0, stream>>>(pcur2, sbbase, offs);
    k_sort3<<<512, 256, 0, stream>>>(stag2, pcur2, sbbase, offs, dinv, csr);
    k_deghist<<<nbl, 256, 0, stream>>>(offs, dhist);
    k_degscan<<<1, DBINS, 0, stream>>>(dhist, dbase);
    k_degfill<<<nbl, 256, 0, stream>>>(offs, dbase, dcur, perm);

    int gemm_grid = (N_NODES + 63) / 64;
    for (int layer = 0; layer < 3; ++layer) {
        k_fold<<<65, 256, 0, stream>>>(Wc + layer * D * D, avec, cvec, layer > 0, WT, rvec);
        if (layer == 0)
            k_gemm<true><<<gemm_grid, 256, 0, stream>>>(x, WT, rvec, dinv, bufY, N_NODES);
        else
            k_gemm<false><<<gemm_grid, 256, 0, stream>>>(bufA, WT, rvec, dinv, bufY, N_NODES);
        k_aggregate<<<N_NODES / 16, 256, 0, stream>>>(
            (const h8*)bufY, offs, csr, dinv, bc + layer * D, perm, (h8*)bufA, part);
        k_bn_coeffs<<<1, 128, 0, stream>>>(part, 32, 256, 128, gc + layer * D,
                                           bec + layer * D, avec, cvec, 1.0f / N_NODES);
    }

    k_starts<<<nbl, 256, 0, stream>>>(batch, starts);
    k_pool<<<N_GRAPHS, 256, 0, stream>>>((const h8*)bufA, starts, avec, cvec, pooled);

    k_dense<128><<<N_GRAPHS, 256, 0, stream>>>(pooled, Wh0, bh0, h0);
    k_head_stats<<<64, 256, 0, stream>>>(h0, sums, sumsq, N_GRAPHS);
    k_bn_coeffs<<<1, 256, 0, stream>>>(stats, 1, 512, 256, gh0, beh0, avec, cvec,
                                       1.0f / N_GRAPHS);
    k_head_apply<<<N_GRAPHS * DH / 4 / 256, 256, 0, stream>>>(h0, avec, cvec);

    k_dense<256><<<N_GRAPHS, 256, 0, stream>>>(h0, Wh1, bh1, h1);
    k_head_stats<<<64, 256, 0, stream>>>(h1, sums, sumsq, N_GRAPHS);
    k_bn_coeffs<<<1, 256, 0, stream>>>(stats, 1, 512, 256, gh1, beh1, avec, cvec,
                                       1.0f / N_GRAPHS);
    k_head_apply<<<N_GRAPHS * DH / 4 / 256, 256, 0, stream>>>(h1, avec, cvec);

    k_final<<<N_GRAPHS / 4, 256, 0, stream>>>(h1, Wout, bout, out);
}

// Round 14
// 527.384 us; speedup vs baseline: 1.9750x; 1.9750x over previous
//
#include <hip/hip_runtime.h>

#define N_NODES 100000
#define N_EDGES 1600000
#define D 128
#define DH 256
#define N_GRAPHS 512
#define EPS 1e-5f
#define NPART 8
#define PSIZE 12500      // N_NODES / NPART
#define FCHUNK 4096      // edges per split chunk
#define PCAP 210000      // staging capacity per partition (~24 sigma)
#define SBSZ 196         // nodes per sub-bucket (64 per partition)
#define SBCAP 4608       // staging capacity per sub-bucket (~26 sigma)
#define CH2 8192         // edges per split2 block
#define DBINS 64         // degree bins for perm sort
#define DCH 2048         // nodes per deg-binning block

typedef _Float16 h8 __attribute__((ext_vector_type(8)));
typedef float f4 __attribute__((ext_vector_type(4)));

// ---------------- preprocessing: fully-coalesced CSR build ----------------

__global__ __launch_bounds__(256) void k_split(const int* __restrict__ src,
                                               const int* __restrict__ dst,
                                               int* __restrict__ pcur,
                                               unsigned* __restrict__ staging) {
    int t = threadIdx.x;
    int base = blockIdx.x * FCHUNK;
    int dbuf[16], sbuf[16], pbuf[16];
#pragma unroll
    for (int j = 0; j < 16; ++j) {
        int i = base + j * 256 + t;
        bool v = i < N_EDGES;
        int d = v ? dst[i] : 0;
        dbuf[j] = d;
        sbuf[j] = v ? src[i] : 0;
        pbuf[j] = v ? d / PSIZE : 8;
    }
    int cnt_loc[8];
#pragma unroll
    for (int p = 0; p < 8; ++p) {
        int c = 0;
#pragma unroll
        for (int j = 0; j < 16; ++j) c += (pbuf[j] == p);
        cnt_loc[p] = c;
    }
    __shared__ int tmp[256][9];
#pragma unroll
    for (int p = 0; p < 8; ++p) tmp[t][p] = cnt_loc[p];
    __syncthreads();
    for (int off = 1; off < 256; off <<= 1) {
        int vals[8];
        if (t >= off) {
#pragma unroll
            for (int p = 0; p < 8; ++p) vals[p] = tmp[t - off][p];
        }
        __syncthreads();
        if (t >= off) {
#pragma unroll
            for (int p = 0; p < 8; ++p) tmp[t][p] += vals[p];
        }
        __syncthreads();
    }
    __shared__ int bbase_s[8];
    if (t < 8) bbase_s[t] = atomicAdd(&pcur[t], tmp[255][t]);
    __syncthreads();
#pragma unroll
    for (int p = 0; p < 8; ++p) {
        int off = bbase_s[p] + tmp[t][p] - cnt_loc[p];
        unsigned* sp = staging + (size_t)p * PCAP;
#pragma unroll
        for (int j = 0; j < 16; ++j) {
            if (pbuf[j] == p) {
                sp[off++] = ((unsigned)(dbuf[j] - p * PSIZE) << 17) | (unsigned)sbuf[j];
            }
        }
    }
}

__global__ __launch_bounds__(256) void k_split2(const unsigned* __restrict__ staging,
                                                const int* __restrict__ pcur,
                                                int* __restrict__ pcur2,
                                                unsigned* __restrict__ stag2) {
    int p = blockIdx.x & 7;
    int chunk = blockIdx.x >> 3;
    int total = min(pcur[p], PCAP);
    int base = chunk * CH2;
    if (base >= total) return;
    int lim = min(CH2, total - base);
    const unsigned* sp = staging + (size_t)p * PCAP + base;
    __shared__ unsigned buf[CH2];
    __shared__ int hist[64], scan[64], cur[64], gbase[64];
    int t = threadIdx.x;
    if (t < 64) hist[t] = 0;
    __syncthreads();
    for (int i = t; i < lim; i += 256) {
        unsigned pk = sp[i];
        atomicAdd(&hist[(pk >> 17) / SBSZ], 1);
    }
    __syncthreads();
    if (t < 64) {
        gbase[t] = atomicAdd(&pcur2[p * 64 + t], hist[t]);
        cur[t] = 0;
    }
    if (t == 0) {
        int acc = 0;
        for (int j = 0; j < 64; ++j) {
            scan[j] = acc;
            acc += hist[j];
        }
    }
    __syncthreads();
    for (int i = t; i < lim; i += 256) {
        unsigned pk = sp[i];
        int sb = (pk >> 17) / SBSZ;
        int r = atomicAdd(&cur[sb], 1);
        buf[scan[sb] + r] = pk;
    }
    __syncthreads();
    for (int sb = 0; sb < 64; ++sb) {
        int n = hist[sb];
        int gb = gbase[sb];
        if (gb >= SBCAP) continue;
        int nn = min(n, SBCAP - gb);
        unsigned* dstp = stag2 + ((size_t)(p * 64 + sb)) * SBCAP + gb;
        for (int i = t; i < nn; i += 256) dstp[i] = buf[scan[sb] + i];
    }
}

__global__ void k_sbscan(int* __restrict__ pcur2, int* __restrict__ sbbase,
                         int* __restrict__ offs) {
    __shared__ int tmp[512];
    int t = threadIdx.x;
    int v = min(pcur2[t], SBCAP);
    tmp[t] = v;
    __syncthreads();
    for (int off = 1; off < 512; off <<= 1) {
        int u = (t >= off) ? tmp[t - off] : 0;
        __syncthreads();
        tmp[t] += u;
        __syncthreads();
    }
    sbbase[t] = tmp[t] - v;
    if (t == 511) offs[N_NODES] = tmp[511];
}

__global__ __launch_bounds__(256) void k_sort3(const unsigned* __restrict__ stag2,
                                               const int* __restrict__ pcur2,
                                               const int* __restrict__ sbbase,
                                               int* __restrict__ offs,
                                               float* __restrict__ dinv,
                                               int* __restrict__ csr) {
    int sb = blockIdx.x;  // 0..511
    int p = sb >> 6, s = sb & 63;
    int n = min(pcur2[sb], SBCAP);
    int gb = sbbase[sb];
    int node0 = p * PSIZE + s * SBSZ;
    int nloc = min(SBSZ, PSIZE - s * SBSZ);
    __shared__ int hist[SBSZ], scan[SBSZ], cur[SBSZ];
    __shared__ int sorted[SBCAP];
    int t = threadIdx.x;
    for (int i = t; i < SBSZ; i += 256) {
        hist[i] = 0;
        cur[i] = 0;
    }
    __syncthreads();
    const unsigned* sp = stag2 + (size_t)sb * SBCAP;
    for (int i = t; i < n; i += 256)
        atomicAdd(&hist[(int)(sp[i] >> 17) - s * SBSZ], 1);
    __syncthreads();
    if (t == 0) {
        int acc = 0;
        for (int j = 0; j < SBSZ; ++j) {
            scan[j] = acc;
            acc += hist[j];
        }
    }
    __syncthreads();
    for (int i = t; i < nloc; i += 256) {
        offs[node0 + i] = gb + scan[i];
        dinv[node0 + i] = rsqrtf((float)(hist[i] + 1));
    }
    for (int i = t; i < n; i += 256) {
        unsigned pk = sp[i];
        int dl = (int)(pk >> 17) - s * SBSZ;
        int r = atomicAdd(&cur[dl], 1);
        sorted[scan[dl] + r] = (int)(pk & 0x1FFFFu);
    }
    __syncthreads();
    for (int i = t; i < n; i += 256) csr[gb + i] = sorted[i];
}

// ---------------- degree-sorted node permutation (anti-divergence) ---------
// Block-local LDS binning; ONE global atomic per (bin, block) -> no storms.

__global__ __launch_bounds__(256) void k_deghist(const int* __restrict__ offs,
                                                 int* __restrict__ dhist) {
    __shared__ int lh[DBINS];
    int t = threadIdx.x;
    if (t < DBINS) lh[t] = 0;
    __syncthreads();
    int base = blockIdx.x * DCH;
    int lim = min(DCH, N_NODES - base);
    for (int i = t; i < lim; i += 256) {
        int deg = min(offs[base + i + 1] - offs[base + i], DBINS - 1);
        atomicAdd(&lh[deg], 1);
    }
    __syncthreads();
    if (t < DBINS && lh[t]) atomicAdd(&dhist[t], lh[t]);
}

__global__ void k_degscan(const int* __restrict__ dhist, int* __restrict__ dbase) {
    __shared__ int tmp[DBINS];
    int t = threadIdx.x;
    int v = dhist[t];
    tmp[t] = v;
    __syncthreads();
    for (int off = 1; off < DBINS; off <<= 1) {
        int u = (t >= off) ? tmp[t - off] : 0;
        __syncthreads();
        tmp[t] += u;
        __syncthreads();
    }
    dbase[t] = tmp[t] - v;
}

__global__ __launch_bounds__(256) void k_degfill(const int* __restrict__ offs,
                                                 const int* __restrict__ dbase,
                                                 int* __restrict__ dcur,
                                                 int* __restrict__ perm) {
    __shared__ int hist[DBINS], scan[DBINS], cur[DBINS], gbase[DBINS];
    __shared__ int buf[DCH];
    int t = threadIdx.x;
    if (t < DBINS) {
        hist[t] = 0;
        cur[t] = 0;
    }
    __syncthreads();
    int base = blockIdx.x * DCH;
    int lim = min(DCH, N_NODES - base);
    for (int i = t; i < lim; i += 256) {
        int deg = min(offs[base + i + 1] - offs[base + i], DBINS - 1);
        atomicAdd(&hist[deg], 1);
    }
    __syncthreads();
    if (t < DBINS) gbase[t] = hist[t] ? atomicAdd(&dcur[t], hist[t]) : 0;
    if (t == 0) {
        int acc = 0;
        for (int j = 0; j < DBINS; ++j) {
            scan[j] = acc;
            acc += hist[j];
        }
    }
    __syncthreads();
    for (int i = t; i < lim; i += 256) {
        int deg = min(offs[base + i + 1] - offs[base + i], DBINS - 1);
        int r = atomicAdd(&cur[deg], 1);
        buf[scan[deg] + r] = base + i;
    }
    __syncthreads();
    for (int b = 0; b < DBINS; ++b) {
        int n = hist[b];
        if (!n) continue;
        int gp = dbase[b] + gbase[b];
        for (int i = t; i < n; i += 256) perm[gp + i] = buf[scan[b] + i];
    }
}

// BN fold merged: blocks 0..63: WT[n][k] = a[k]*W[k][n] (fp16); block 64: r[j]
__global__ void k_fold(const float* __restrict__ W, const float* __restrict__ a,
                       const float* __restrict__ c, int use_bn,
                       _Float16* __restrict__ WT, float* __restrict__ r) {
    if (blockIdx.x < 64) {
        int idx = blockIdx.x * 256 + threadIdx.x;
        int n = idx >> 7, k = idx & 127;
        float s = use_bn ? a[k] : 1.0f;
        WT[idx] = (_Float16)(s * W[k * D + n]);
    } else if (threadIdx.x < 128) {
        int j = threadIdx.x;
        float s = 0.f;
        if (use_bn)
            for (int k = 0; k < D; ++k) s = fmaf(c[k], W[k * D + j], s);
        r[j] = s;
    }
}

// ---------------- MFMA GEMM: Y'[n] = dinv[n]*(X[n]@W + r), fp16 out ---------
template <bool F32IN>
__global__ __launch_bounds__(256) void k_gemm(const void* __restrict__ Xv,
                                              const _Float16* __restrict__ WT,
                                              const float* __restrict__ radd,
                                              const float* __restrict__ dinv,
                                              _Float16* __restrict__ Y, int nrows) {
    __shared__ _Float16 Wl[128][136];
    __shared__ _Float16 Yl[64][136];
    int t = threadIdx.x;
    {
        const h8* src = (const h8*)WT;
        for (int i = t; i < 128 * 16; i += 256) {
            int r = i >> 4, c = i & 15;
            *(h8*)&Wl[r][c * 8] = src[i];
        }
    }
    int wave = t >> 6;
    int lane = t & 63;
    int l15 = lane & 15;
    int quad = lane >> 4;
    int rowblk = blockIdx.x * 64;
    int row0 = rowblk + wave * 16;

    h8 zero8;
#pragma unroll
    for (int j = 0; j < 8; ++j) zero8[j] = (_Float16)0;

    h8 a[4];
    bool inb = (row0 + l15) < nrows;
#pragma unroll
    for (int kt = 0; kt < 4; ++kt) a[kt] = zero8;
    if (inb) {
        if constexpr (F32IN) {
            const float* xrow = (const float*)Xv + (size_t)(row0 + l15) * D + quad * 8;
#pragma unroll
            for (int kt = 0; kt < 4; ++kt) {
                float4 u = *(const float4*)(xrow + kt * 32);
                float4 w = *(const float4*)(xrow + kt * 32 + 4);
                h8 o;
                o[0] = (_Float16)u.x; o[1] = (_Float16)u.y;
                o[2] = (_Float16)u.z; o[3] = (_Float16)u.w;
                o[4] = (_Float16)w.x; o[5] = (_Float16)w.y;
                o[6] = (_Float16)w.z; o[7] = (_Float16)w.w;
                a[kt] = o;
            }
        } else {
            const _Float16* xrow = (const _Float16*)Xv + (size_t)(row0 + l15) * D + quad * 8;
#pragma unroll
            for (int kt = 0; kt < 4; ++kt) a[kt] = *(const h8*)(xrow + kt * 32);
        }
    }

    __syncthreads();

    f4 acc[8];
#pragma unroll
    for (int n = 0; n < 8; ++n) {
        acc[n][0] = 0.f; acc[n][1] = 0.f; acc[n][2] = 0.f; acc[n][3] = 0.f;
#pragma unroll
        for (int kt = 0; kt < 4; ++kt) {
            h8 b = *(const h8*)&Wl[n * 16 + l15][kt * 32 + quad * 8];
            acc[n] = __builtin_amdgcn_mfma_f32_16x16x32_f16(a[kt], b, acc[n], 0, 0, 0);
        }
    }
    float dv[4];
    int rbase = rowblk + wave * 16 + quad * 4;
#pragma unroll
    for (int i = 0; i < 4; ++i)
        dv[i] = (rbase + i < nrows) ? dinv[rbase + i] : 0.f;
#pragma unroll
    for (int n = 0; n < 8; ++n) {
        float r = radd[n * 16 + l15];
#pragma unroll
        for (int i = 0; i < 4; ++i)
            Yl[wave * 16 + quad * 4 + i][n * 16 + l15] = (_Float16)((acc[n][i] + r) * dv[i]);
    }
    __syncthreads();
    for (int i = t; i < 64 * 16; i += 256) {
        int r = i >> 4, c = i & 15;
        if (rowblk + r < nrows)
            *(h8*)&Y[(size_t)(rowblk + r) * D + c * 8] = *(h8*)&Yl[r][c * 8];
    }
}

// ---------------- aggregate + relu + fused BN partial stats ----------------
__global__ __launch_bounds__(256) void k_aggregate(const h8* __restrict__ Y8,
                                                   const int* __restrict__ offs,
                                                   const int* __restrict__ csr,
                                                   const float* __restrict__ dinv,
                                                   const float* __restrict__ bias,
                                                   const int* __restrict__ perm,
                                                   h8* __restrict__ A8,
                                                   float* __restrict__ part) {
    int grp = threadIdx.x >> 4;
    int lane = threadIdx.x & 15;
    int node = perm[blockIdx.x * 16 + grp];
    int beg = offs[node], end = offs[node + 1];
    float dn = dinv[node];
    float acc[8];
    h8 y = Y8[(size_t)node * 16 + lane];
#pragma unroll
    for (int i = 0; i < 8; ++i) acc[i] = (float)y[i];
    int e = beg;
    for (; e + 7 < end; e += 8) {
        int s0 = csr[e], s1 = csr[e + 1], s2 = csr[e + 2], s3 = csr[e + 3];
        int s4 = csr[e + 4], s5 = csr[e + 5], s6 = csr[e + 6], s7 = csr[e + 7];
        h8 v0 = Y8[(size_t)s0 * 16 + lane];
        h8 v1 = Y8[(size_t)s1 * 16 + lane];
        h8 v2 = Y8[(size_t)s2 * 16 + lane];
        h8 v3 = Y8[(size_t)s3 * 16 + lane];
        h8 v4 = Y8[(size_t)s4 * 16 + lane];
        h8 v5 = Y8[(size_t)s5 * 16 + lane];
        h8 v6 = Y8[(size_t)s6 * 16 + lane];
        h8 v7 = Y8[(size_t)s7 * 16 + lane];
#pragma unroll
        for (int i = 0; i < 8; ++i) {
            acc[i] += (float)v0[i] + (float)v1[i] + (float)v2[i] + (float)v3[i];
            acc[i] += (float)v4[i] + (float)v5[i] + (float)v6[i] + (float)v7[i];
        }
    }
    if (e + 3 < end) {
        int s0 = csr[e], s1 = csr[e + 1], s2 = csr[e + 2], s3 = csr[e + 3];
        h8 v0 = Y8[(size_t)s0 * 16 + lane];
        h8 v1 = Y8[(size_t)s1 * 16 + lane];
        h8 v2 = Y8[(size_t)s2 * 16 + lane];
        h8 v3 = Y8[(size_t)s3 * 16 + lane];
#pragma unroll
        for (int i = 0; i < 8; ++i)
            acc[i] += (float)v0[i] + (float)v1[i] + (float)v2[i] + (float)v3[i];
        e += 4;
    }
    for (; e < end; ++e) {
        int s = csr[e];
        h8 v = Y8[(size_t)s * 16 + lane];
#pragma unroll
        for (int i = 0; i < 8; ++i) acc[i] += (float)v[i];
    }
    __shared__ float red[16][128];
    h8 o;
#pragma unroll
    for (int i = 0; i < 8; ++i) {
        float v = fmaxf(fmaf(acc[i], dn, bias[lane * 8 + i]), 0.f);
        o[i] = (_Float16)v;
        red[grp][lane * 8 + i] = v;
    }
    __builtin_nontemporal_store(o, &A8[(size_t)node * 16 + lane]);
    __syncthreads();
    if (threadIdx.x < 128) {
        int c = threadIdx.x;
        float s = 0.f, s2 = 0.f;
#pragma unroll
        for (int g = 0; g < 16; ++g) {
            float v = red[g][c];
            s += v;
            s2 = fmaf(v, v, s2);
        }
        float* p = part + (size_t)(blockIdx.x & 31) * 256;
        atomicAdd(&p[c], s);
        atomicAdd(&p[128 + c], s2);
    }
}

__global__ void k_bn_coeffs(float* __restrict__ part, int stripes, int stride,
                            int coff, const float* __restrict__ g,
                            const float* __restrict__ beta, float* __restrict__ a,
                            float* __restrict__ c, float inv_n) {
    int i = threadIdx.x;
    float s = 0.f, s2 = 0.f;
    for (int st = 0; st < stripes; ++st) {
        s += part[st * stride + i];
        s2 += part[st * stride + coff + i];
        part[st * stride + i] = 0.f;
        part[st * stride + coff + i] = 0.f;
    }
    float m = s * inv_n;
    float v = s2 * inv_n - m * m;
    float ai = g[i] * rsqrtf(v + EPS);
    a[i] = ai;
    c[i] = beta[i] - m * ai;
}

// ---------------- pooling + MLP head ----------------

__global__ void k_starts(const int* __restrict__ batch, int* __restrict__ starts) {
    int n = blockIdx.x * 256 + threadIdx.x;
    if (n >= N_NODES) return;
    int b = batch[n];
    int prev = (n == 0) ? -1 : batch[n - 1];
    for (int g = prev + 1; g <= b; ++g) starts[g] = n;
    if (n == N_NODES - 1)
        for (int g = b + 1; g <= N_GRAPHS; ++g) starts[g] = N_NODES;
}

__global__ __launch_bounds__(256) void k_pool(const h8* __restrict__ x8,
                                              const int* __restrict__ starts,
                                              const float* __restrict__ a,
                                              const float* __restrict__ c,
                                              float* __restrict__ pooled) {
    int g = blockIdx.x;
    int grp = threadIdx.x >> 4;
    int lane = threadIdx.x & 15;
    int beg = starts[g], end = starts[g + 1];
    float s[8] = {};
    for (int n = beg + grp; n < end; n += 16) {
        h8 v = x8[(size_t)n * 16 + lane];
#pragma unroll
        for (int i = 0; i < 8; ++i) s[i] += (float)v[i];
    }
    __shared__ float red[16][128];
#pragma unroll
    for (int i = 0; i < 8; ++i) red[grp][lane * 8 + i] = s[i];
    __syncthreads();
    if (threadIdx.x < 128) {
        int ch = threadIdx.x;
        float t = 0.f;
#pragma unroll
        for (int gg = 0; gg < 16; ++gg) t += red[gg][ch];
        float cnt = (float)(end - beg);
        pooled[g * D + ch] = fmaf(a[ch], t, cnt * c[ch]);
    }
}

template <int K>
__global__ __launch_bounds__(256) void k_dense(const float* __restrict__ in,
                                               const float* __restrict__ W,
                                               const float* __restrict__ b,
                                               float* __restrict__ out) {
    __shared__ float inl[K];
    int row = blockIdx.x;
    for (int k = threadIdx.x; k < K; k += 256) inl[k] = in[row * K + k];
    __syncthreads();
    int j = threadIdx.x;
    float acc = b[j];
#pragma unroll
    for (int k = 0; k < K; ++k) acc = fmaf(inl[k], W[k * 256 + j], acc);
    out[row * 256 + j] = fmaxf(acc, 0.0f);
}

__global__ void k_head_stats(const float* __restrict__ x, float* __restrict__ sums,
                             float* __restrict__ sumsq, int rows) {
    int c = threadIdx.x;
    float s = 0.f, s2 = 0.f;
    int r0 = blockIdx.x * 8;
    int r1 = min(r0 + 8, rows);
    for (int r = r0; r < r1; ++r) {
        float v = x[r * DH + c];
        s += v;
        s2 = fmaf(v, v, s2);
    }
    atomicAdd(&sums[c], s);
    atomicAdd(&sumsq[c], s2);
}

__global__ void k_head_apply(float* __restrict__ x, const float* __restrict__ a,
                             const float* __restrict__ c) {
    int i = blockIdx.x * 256 + threadIdx.x;
    float4 v = ((float4*)x)[i];
    int col = (i << 2) & 255;
    v.x = fmaf(v.x, a[col], c[col]);
    v.y = fmaf(v.y, a[col + 1], c[col + 1]);
    v.z = fmaf(v.z, a[col + 2], c[col + 2]);
    v.w = fmaf(v.w, a[col + 3], c[col + 3]);
    ((float4*)x)[i] = v;
}

__global__ void k_final(const float* __restrict__ h, const float* __restrict__ Wout,
                        const float* __restrict__ bout, float* __restrict__ out) {
    int g = blockIdx.x * 4 + (threadIdx.x >> 6);
    int lane = threadIdx.x & 63;
    float4 v = ((const float4*)(h + g * DH))[lane];
    float4 w = ((const float4*)Wout)[lane];
    float acc = v.x * w.x + v.y * w.y + v.z * w.z + v.w * w.w;
#pragma unroll
    for (int off = 32; off; off >>= 1) acc += __shfl_down(acc, off, 64);
    if (lane == 0) out[g] = acc + bout[0];
}

// ---------------- launch ----------------

extern "C" void kernel_launch(void* const* d_in, const int* in_sizes, int n_in,
                              void* d_out, int out_size, void* d_ws, size_t ws_size,
                              hipStream_t stream) {
    const float* x = (const float*)d_in[0];
    const int* ei = (const int*)d_in[1];
    const int* batch = (const int*)d_in[2];
    const float* Wc = (const float*)d_in[3];
    const float* bc = (const float*)d_in[4];
    const float* gc = (const float*)d_in[5];
    const float* bec = (const float*)d_in[6];
    const float* Wh0 = (const float*)d_in[7];
    const float* bh0 = (const float*)d_in[8];
    const float* gh0 = (const float*)d_in[9];
    const float* beh0 = (const float*)d_in[10];
    const float* Wh1 = (const float*)d_in[11];
    const float* bh1 = (const float*)d_in[12];
    const float* gh1 = (const float*)d_in[13];
    const float* beh1 = (const float*)d_in[14];
    const float* Wout = (const float*)d_in[15];
    const float* bout = (const float*)d_in[16];
    float* out = (float*)d_out;

    const int* src = ei;
    const int* dst = ei + N_EDGES;

    char* base = (char*)d_ws;
    size_t woff = 0;
    auto alloc = [&](size_t bytes) -> char* {
        char* p = base + woff;
        woff = (woff + bytes + 255) & ~(size_t)255;
        return p;
    };
    _Float16* bufY = (_Float16*)alloc(sizeof(_Float16) * (size_t)N_NODES * D);
    _Float16* bufA = (_Float16*)alloc(sizeof(_Float16) * (size_t)N_NODES * D);
    float* dinv = (float*)alloc(sizeof(float) * N_NODES);
    int* csr = (int*)alloc(sizeof(int) * N_EDGES);
    int* perm = (int*)alloc(sizeof(int) * N_NODES);
    unsigned* staging = (unsigned*)alloc(sizeof(unsigned) * 8 * PCAP);
    unsigned* stag2 = (unsigned*)alloc(sizeof(unsigned) * 512 * SBCAP);
    // single zeroed region: pcur(64) + pcur2(512) + dhist(64) + dcur(64) + part + stats
    size_t zero_bytes =
        sizeof(int) * (64 + 512 + 64 + 64) + sizeof(float) * (32 * 256 + 512);
    char* zero_base = alloc(zero_bytes);
    int* pcur = (int*)zero_base;
    int* pcur2 = pcur + 64;
    int* dhist = pcur2 + 512;
    int* dcur = dhist + 64;
    float* part = (float*)(dcur + 64);
    float* stats = part + 32 * 256;
    float* sums = stats;
    float* sumsq = stats + 256;
    int* offs = (int*)alloc(sizeof(int) * (N_NODES + 1));
    int* sbbase = (int*)alloc(sizeof(int) * 512);
    int* dbase = (int*)alloc(sizeof(int) * 64);
    float* avec = (float*)alloc(sizeof(float) * 256);
    float* cvec = (float*)alloc(sizeof(float) * 256);
    _Float16* WT = (_Float16*)alloc(sizeof(_Float16) * D * D);
    float* rvec = (float*)alloc(sizeof(float) * 128);
    int* starts = (int*)alloc(sizeof(int) * (N_GRAPHS + 1));
    float* pooled = (float*)alloc(sizeof(float) * N_GRAPHS * D);
    float* h0 = (float*)alloc(sizeof(float) * N_GRAPHS * DH);
    float* h1 = (float*)alloc(sizeof(float) * N_GRAPHS * DH);

    hipMemsetAsync(zero_base, 0, zero_bytes, stream);

    int nbl = (N_NODES + 255) / 256;
    int split_grid = (N_EDGES + FCHUNK - 1) / FCHUNK;
    int split2_grid = ((PCAP + CH2 - 1) / CH2) * 8;
    int dgrid = (N_NODES + DCH - 1) / DCH;
    k_split<<<split_grid, 256, 0, stream>>>(src, dst, pcur, staging);
    k_split2<<<split2_grid, 256, 0, stream>>>(staging, pcur, pcur2, stag2);
    k_sbscan<<<1, 512, 0, stream>>>(pcur2, sbbase, offs);
    k_sort3<<<512, 256, 0, stream>>>(stag2, pcur2, sbbase, offs, dinv, csr);
    k_deghist<<<dgrid, 256, 0, stream>>>(offs, dhist);
    k_degscan<<<1, DBINS, 0, stream>>>(dhist, dbase);
    k_degfill<<<dgrid, 256, 0, stream>>>(offs, dbase, dcur, perm);

    int gemm_grid = (N_NODES + 63) / 64;
    for (int layer = 0; layer < 3; ++layer) {
        k_fold<<<65, 256, 0, stream>>>(Wc + layer * D * D, avec, cvec, layer > 0, WT, rvec);
        if (layer == 0)
            k_gemm<true><<<gemm_grid, 256, 0, stream>>>(x, WT, rvec, dinv, bufY, N_NODES);
        else
            k_gemm<false><<<gemm_grid, 256, 0, stream>>>(bufA, WT, rvec, dinv, bufY, N_NODES);
        k_aggregate<<<N_NODES / 16, 256, 0, stream>>>(
            (const h8*)bufY, offs, csr, dinv, bc + layer * D, perm, (h8*)bufA, part);
        k_bn_coeffs<<<1, 128, 0, stream>>>(part, 32, 256, 128, gc + layer * D,
                                           bec + layer * D, avec, cvec, 1.0f / N_NODES);
    }

    k_starts<<<nbl, 256, 0, stream>>>(batch, starts);
    k_pool<<<N_GRAPHS, 256, 0, stream>>>((const h8*)bufA, starts, avec, cvec, pooled);

    k_dense<128><<<N_GRAPHS, 256, 0, stream>>>(pooled, Wh0, bh0, h0);
    k_head_stats<<<64, 256, 0, stream>>>(h0, sums, sumsq, N_GRAPHS);
    k_bn_coeffs<<<1, 256, 0, stream>>>(stats, 1, 512, 256, gh0, beh0, avec, cvec,
                                       1.0f / N_GRAPHS);
    k_head_apply<<<N_GRAPHS * DH / 4 / 256, 256, 0, stream>>>(h0, avec, cvec);

    k_dense<256><<<N_GRAPHS, 256, 0, stream>>>(h0, Wh1, bh1, h1);
    k_head_stats<<<64, 256, 0, stream>>>(h1, sums, sumsq, N_GRAPHS);
    k_bn_coeffs<<<1, 256, 0, stream>>>(stats, 1, 512, 256, gh1, beh1, avec, cvec,
                                       1.0f / N_GRAPHS);
    k_head_apply<<<N_GRAPHS * DH / 4 / 256, 256, 0, stream>>>(h1, avec, cvec);

    k_final<<<N_GRAPHS / 4, 256, 0, stream>>>(h1, Wout, bout, out);
}

// Round 15
// 479.213 us; speedup vs baseline: 2.1736x; 1.1005x over previous
//
#include <hip/hip_runtime.h>

#define N_NODES 100000
#define N_EDGES 1600000
#define D 128
#define DH 256
#define N_GRAPHS 512
#define EPS 1e-5f
#define NPART 8
#define PSIZE 12500      // N_NODES / NPART
#define FCHUNK 4096      // edges per split chunk
#define PCAP 210000      // staging capacity per partition (~24 sigma)
#define SBSZ 196         // nodes per sub-bucket (64 per partition)
#define SBCAP 4608       // staging capacity per sub-bucket (~26 sigma)
#define CH2 8192         // edges per split2 block

typedef _Float16 h8 __attribute__((ext_vector_type(8)));
typedef float f4 __attribute__((ext_vector_type(4)));

// ---------------- preprocessing: fully-coalesced CSR build ----------------

__global__ __launch_bounds__(256) void k_split(const int* __restrict__ src,
                                               const int* __restrict__ dst,
                                               int* __restrict__ pcur,
                                               unsigned* __restrict__ staging) {
    int t = threadIdx.x;
    int base = blockIdx.x * FCHUNK;
    int dbuf[16], sbuf[16], pbuf[16];
#pragma unroll
    for (int j = 0; j < 16; ++j) {
        int i = base + j * 256 + t;
        bool v = i < N_EDGES;
        int d = v ? dst[i] : 0;
        dbuf[j] = d;
        sbuf[j] = v ? src[i] : 0;
        pbuf[j] = v ? d / PSIZE : 8;
    }
    int cnt_loc[8];
#pragma unroll
    for (int p = 0; p < 8; ++p) {
        int c = 0;
#pragma unroll
        for (int j = 0; j < 16; ++j) c += (pbuf[j] == p);
        cnt_loc[p] = c;
    }
    __shared__ int tmp[256][9];
#pragma unroll
    for (int p = 0; p < 8; ++p) tmp[t][p] = cnt_loc[p];
    __syncthreads();
    for (int off = 1; off < 256; off <<= 1) {
        int vals[8];
        if (t >= off) {
#pragma unroll
            for (int p = 0; p < 8; ++p) vals[p] = tmp[t - off][p];
        }
        __syncthreads();
        if (t >= off) {
#pragma unroll
            for (int p = 0; p < 8; ++p) tmp[t][p] += vals[p];
        }
        __syncthreads();
    }
    __shared__ int bbase_s[8];
    if (t < 8) bbase_s[t] = atomicAdd(&pcur[t], tmp[255][t]);
    __syncthreads();
#pragma unroll
    for (int p = 0; p < 8; ++p) {
        int off = bbase_s[p] + tmp[t][p] - cnt_loc[p];
        unsigned* sp = staging + (size_t)p * PCAP;
#pragma unroll
        for (int j = 0; j < 16; ++j) {
            if (pbuf[j] == p) {
                sp[off++] = ((unsigned)(dbuf[j] - p * PSIZE) << 17) | (unsigned)sbuf[j];
            }
        }
    }
}

__global__ __launch_bounds__(256) void k_split2(const unsigned* __restrict__ staging,
                                                const int* __restrict__ pcur,
                                                int* __restrict__ pcur2,
                                                unsigned* __restrict__ stag2) {
    int p = blockIdx.x & 7;
    int chunk = blockIdx.x >> 3;
    int total = min(pcur[p], PCAP);
    int base = chunk * CH2;
    if (base >= total) return;
    int lim = min(CH2, total - base);
    const unsigned* sp = staging + (size_t)p * PCAP + base;
    __shared__ unsigned buf[CH2];
    __shared__ int hist[64], scan[64], cur[64], gbase[64];
    int t = threadIdx.x;
    if (t < 64) hist[t] = 0;
    __syncthreads();
    for (int i = t; i < lim; i += 256) {
        unsigned pk = sp[i];
        atomicAdd(&hist[(pk >> 17) / SBSZ], 1);
    }
    __syncthreads();
    if (t < 64) {
        gbase[t] = atomicAdd(&pcur2[p * 64 + t], hist[t]);
        cur[t] = 0;
    }
    if (t == 0) {
        int acc = 0;
        for (int j = 0; j < 64; ++j) {
            scan[j] = acc;
            acc += hist[j];
        }
    }
    __syncthreads();
    for (int i = t; i < lim; i += 256) {
        unsigned pk = sp[i];
        int sb = (pk >> 17) / SBSZ;
        int r = atomicAdd(&cur[sb], 1);
        buf[scan[sb] + r] = pk;
    }
    __syncthreads();
    for (int sb = 0; sb < 64; ++sb) {
        int n = hist[sb];
        int gb = gbase[sb];
        if (gb >= SBCAP) continue;
        int nn = min(n, SBCAP - gb);
        unsigned* dstp = stag2 + ((size_t)(p * 64 + sb)) * SBCAP + gb;
        for (int i = t; i < nn; i += 256) dstp[i] = buf[scan[sb] + i];
    }
}

__global__ void k_sbscan(int* __restrict__ pcur2, int* __restrict__ sbbase,
                         int* __restrict__ offs) {
    __shared__ int tmp[512];
    int t = threadIdx.x;
    int v = min(pcur2[t], SBCAP);
    tmp[t] = v;
    __syncthreads();
    for (int off = 1; off < 512; off <<= 1) {
        int u = (t >= off) ? tmp[t - off] : 0;
        __syncthreads();
        tmp[t] += u;
        __syncthreads();
    }
    sbbase[t] = tmp[t] - v;
    if (t == 511) offs[N_NODES] = tmp[511];
}

__global__ __launch_bounds__(256) void k_sort3(const unsigned* __restrict__ stag2,
                                               const int* __restrict__ pcur2,
                                               const int* __restrict__ sbbase,
                                               int* __restrict__ offs,
                                               float* __restrict__ dinv,
                                               int* __restrict__ csr) {
    int sb = blockIdx.x;  // 0..511
    int p = sb >> 6, s = sb & 63;
    int n = min(pcur2[sb], SBCAP);
    int gb = sbbase[sb];
    int node0 = p * PSIZE + s * SBSZ;
    int nloc = min(SBSZ, PSIZE - s * SBSZ);
    __shared__ int hist[SBSZ], scan[SBSZ], cur[SBSZ];
    __shared__ int sorted[SBCAP];
    int t = threadIdx.x;
    for (int i = t; i < SBSZ; i += 256) {
        hist[i] = 0;
        cur[i] = 0;
    }
    __syncthreads();
    const unsigned* sp = stag2 + (size_t)sb * SBCAP;
    for (int i = t; i < n; i += 256)
        atomicAdd(&hist[(int)(sp[i] >> 17) - s * SBSZ], 1);
    __syncthreads();
    if (t == 0) {
        int acc = 0;
        for (int j = 0; j < SBSZ; ++j) {
            scan[j] = acc;
            acc += hist[j];
        }
    }
    __syncthreads();
    for (int i = t; i < nloc; i += 256) {
        offs[node0 + i] = gb + scan[i];
        dinv[node0 + i] = rsqrtf((float)(hist[i] + 1));
    }
    for (int i = t; i < n; i += 256) {
        unsigned pk = sp[i];
        int dl = (int)(pk >> 17) - s * SBSZ;
        int r = atomicAdd(&cur[dl], 1);
        sorted[scan[dl] + r] = (int)(pk & 0x1FFFFu);
    }
    __syncthreads();
    for (int i = t; i < n; i += 256) csr[gb + i] = sorted[i];
}

// ---- BN fold + coeff computation fused: each block redundantly reduces the
// 32x256 striped partials (L2-hit) -> a[k],c[k]; blocks 0..63 scale W into
// WT; block 64 computes r[j] = sum_k c[k] W[k][j].
__global__ __launch_bounds__(256) void k_fold(const float* __restrict__ W,
                                              const float* __restrict__ part,
                                              const float* __restrict__ g,
                                              const float* __restrict__ beta,
                                              int use_bn,
                                              _Float16* __restrict__ WT,
                                              float* __restrict__ r) {
    __shared__ float as_[128], cs_[128];
    int t = threadIdx.x;
    if (use_bn) {
        if (t < 128) {
            float s = 0.f, s2 = 0.f;
            for (int st = 0; st < 32; ++st) {
                s += part[st * 256 + t];
                s2 += part[st * 256 + 128 + t];
            }
            float m = s * (1.0f / N_NODES);
            float v = s2 * (1.0f / N_NODES) - m * m;
            float ai = g[t] * rsqrtf(v + EPS);
            as_[t] = ai;
            cs_[t] = beta[t] - m * ai;
        }
        __syncthreads();
    }
    if (blockIdx.x < 64) {
        int idx = blockIdx.x * 256 + t;
        int n = idx >> 7, k = idx & 127;
        float s = use_bn ? as_[k] : 1.0f;
        WT[idx] = (_Float16)(s * W[k * D + n]);
    } else if (t < 128) {
        float s = 0.f;
        if (use_bn)
            for (int k = 0; k < D; ++k) s = fmaf(cs_[k], W[k * D + t], s);
        r[t] = s;
    }
}

// ---------------- MFMA GEMM: Y'[n] = dinv[n]*(X[n]@W + r), fp16 out ---------
template <bool F32IN>
__global__ __launch_bounds__(256) void k_gemm(const void* __restrict__ Xv,
                                              const _Float16* __restrict__ WT,
                                              const float* __restrict__ radd,
                                              const float* __restrict__ dinv,
                                              _Float16* __restrict__ Y, int nrows) {
    __shared__ _Float16 Wl[128][136];
    __shared__ _Float16 Yl[64][136];
    int t = threadIdx.x;
    {
        const h8* src = (const h8*)WT;
        for (int i = t; i < 128 * 16; i += 256) {
            int r = i >> 4, c = i & 15;
            *(h8*)&Wl[r][c * 8] = src[i];
        }
    }
    int wave = t >> 6;
    int lane = t & 63;
    int l15 = lane & 15;
    int quad = lane >> 4;
    int rowblk = blockIdx.x * 64;
    int row0 = rowblk + wave * 16;

    h8 zero8;
#pragma unroll
    for (int j = 0; j < 8; ++j) zero8[j] = (_Float16)0;

    h8 a[4];
    bool inb = (row0 + l15) < nrows;
#pragma unroll
    for (int kt = 0; kt < 4; ++kt) a[kt] = zero8;
    if (inb) {
        if constexpr (F32IN) {
            const float* xrow = (const float*)Xv + (size_t)(row0 + l15) * D + quad * 8;
#pragma unroll
            for (int kt = 0; kt < 4; ++kt) {
                float4 u = *(const float4*)(xrow + kt * 32);
                float4 w = *(const float4*)(xrow + kt * 32 + 4);
                h8 o;
                o[0] = (_Float16)u.x; o[1] = (_Float16)u.y;
                o[2] = (_Float16)u.z; o[3] = (_Float16)u.w;
                o[4] = (_Float16)w.x; o[5] = (_Float16)w.y;
                o[6] = (_Float16)w.z; o[7] = (_Float16)w.w;
                a[kt] = o;
            }
        } else {
            const _Float16* xrow = (const _Float16*)Xv + (size_t)(row0 + l15) * D + quad * 8;
#pragma unroll
            for (int kt = 0; kt < 4; ++kt) a[kt] = *(const h8*)(xrow + kt * 32);
        }
    }

    __syncthreads();

    f4 acc[8];
#pragma unroll
    for (int n = 0; n < 8; ++n) {
        acc[n][0] = 0.f; acc[n][1] = 0.f; acc[n][2] = 0.f; acc[n][3] = 0.f;
#pragma unroll
        for (int kt = 0; kt < 4; ++kt) {
            h8 b = *(const h8*)&Wl[n * 16 + l15][kt * 32 + quad * 8];
            acc[n] = __builtin_amdgcn_mfma_f32_16x16x32_f16(a[kt], b, acc[n], 0, 0, 0);
        }
    }
    float dv[4];
    int rbase = rowblk + wave * 16 + quad * 4;
#pragma unroll
    for (int i = 0; i < 4; ++i)
        dv[i] = (rbase + i < nrows) ? dinv[rbase + i] : 0.f;
#pragma unroll
    for (int n = 0; n < 8; ++n) {
        float r = radd[n * 16 + l15];
#pragma unroll
        for (int i = 0; i < 4; ++i)
            Yl[wave * 16 + quad * 4 + i][n * 16 + l15] = (_Float16)((acc[n][i] + r) * dv[i]);
    }
    __syncthreads();
    for (int i = t; i < 64 * 16; i += 256) {
        int r = i >> 4, c = i & 15;
        if (rowblk + r < nrows)
            *(h8*)&Y[(size_t)(rowblk + r) * D + c * 8] = *(h8*)&Yl[r][c * 8];
    }
}

// ---------------- aggregate + relu + fused BN partial stats ----------------
__global__ __launch_bounds__(256) void k_aggregate(const h8* __restrict__ Y8,
                                                   const int* __restrict__ offs,
                                                   const int* __restrict__ csr,
                                                   const float* __restrict__ dinv,
                                                   const float* __restrict__ bias,
                                                   h8* __restrict__ A8,
                                                   float* __restrict__ part) {
    int grp = threadIdx.x >> 4;
    int lane = threadIdx.x & 15;
    int node = blockIdx.x * 16 + grp;
    int beg = offs[node], end = offs[node + 1];
    float dn = dinv[node];
    float acc[8];
    h8 y = Y8[(size_t)node * 16 + lane];
#pragma unroll
    for (int i = 0; i < 8; ++i) acc[i] = (float)y[i];
    int e = beg;
    for (; e + 7 < end; e += 8) {
        int s0 = csr[e], s1 = csr[e + 1], s2 = csr[e + 2], s3 = csr[e + 3];
        int s4 = csr[e + 4], s5 = csr[e + 5], s6 = csr[e + 6], s7 = csr[e + 7];
        h8 v0 = Y8[(size_t)s0 * 16 + lane];
        h8 v1 = Y8[(size_t)s1 * 16 + lane];
        h8 v2 = Y8[(size_t)s2 * 16 + lane];
        h8 v3 = Y8[(size_t)s3 * 16 + lane];
        h8 v4 = Y8[(size_t)s4 * 16 + lane];
        h8 v5 = Y8[(size_t)s5 * 16 + lane];
        h8 v6 = Y8[(size_t)s6 * 16 + lane];
        h8 v7 = Y8[(size_t)s7 * 16 + lane];
#pragma unroll
        for (int i = 0; i < 8; ++i) {
            acc[i] += (float)v0[i] + (float)v1[i] + (float)v2[i] + (float)v3[i];
            acc[i] += (float)v4[i] + (float)v5[i] + (float)v6[i] + (float)v7[i];
        }
    }
    if (e + 3 < end) {
        int s0 = csr[e], s1 = csr[e + 1], s2 = csr[e + 2], s3 = csr[e + 3];
        h8 v0 = Y8[(size_t)s0 * 16 + lane];
        h8 v1 = Y8[(size_t)s1 * 16 + lane];
        h8 v2 = Y8[(size_t)s2 * 16 + lane];
        h8 v3 = Y8[(size_t)s3 * 16 + lane];
#pragma unroll
        for (int i = 0; i < 8; ++i)
            acc[i] += (float)v0[i] + (float)v1[i] + (float)v2[i] + (float)v3[i];
        e += 4;
    }
    for (; e < end; ++e) {
        int s = csr[e];
        h8 v = Y8[(size_t)s * 16 + lane];
#pragma unroll
        for (int i = 0; i < 8; ++i) acc[i] += (float)v[i];
    }
    __shared__ float red[16][128];
    h8 o;
#pragma unroll
    for (int i = 0; i < 8; ++i) {
        float v = fmaxf(fmaf(acc[i], dn, bias[lane * 8 + i]), 0.f);
        o[i] = (_Float16)v;
        red[grp][lane * 8 + i] = v;
    }
    __builtin_nontemporal_store(o, &A8[(size_t)node * 16 + lane]);
    __syncthreads();
    if (threadIdx.x < 128) {
        int c = threadIdx.x;
        float s = 0.f, s2 = 0.f;
#pragma unroll
        for (int g = 0; g < 16; ++g) {
            float v = red[g][c];
            s += v;
            s2 = fmaf(v, v, s2);
        }
        float* p = part + (size_t)(blockIdx.x & 31) * 256;
        atomicAdd(&p[c], s);
        atomicAdd(&p[128 + c], s2);
    }
}

// BN coeffs from striped partials (no re-zero; buffers are use-once)
__global__ void k_bn_coeffs(const float* __restrict__ part, int stripes, int stride,
                            int coff, const float* __restrict__ g,
                            const float* __restrict__ beta, float* __restrict__ a,
                            float* __restrict__ c, float inv_n) {
    int i = threadIdx.x;
    float s = 0.f, s2 = 0.f;
    for (int st = 0; st < stripes; ++st) {
        s += part[st * stride + i];
        s2 += part[st * stride + coff + i];
    }
    float m = s * inv_n;
    float v = s2 * inv_n - m * m;
    float ai = g[i] * rsqrtf(v + EPS);
    a[i] = ai;
    c[i] = beta[i] - m * ai;
}

// ---------------- pooling + MLP head ----------------

__global__ void k_starts(const int* __restrict__ batch, int* __restrict__ starts) {
    int n = blockIdx.x * 256 + threadIdx.x;
    if (n >= N_NODES) return;
    int b = batch[n];
    int prev = (n == 0) ? -1 : batch[n - 1];
    for (int g = prev + 1; g <= b; ++g) starts[g] = n;
    if (n == N_NODES - 1)
        for (int g = b + 1; g <= N_GRAPHS; ++g) starts[g] = N_NODES;
}

__global__ __launch_bounds__(256) void k_pool(const h8* __restrict__ x8,
                                              const int* __restrict__ starts,
                                              const float* __restrict__ a,
                                              const float* __restrict__ c,
                                              float* __restrict__ pooled) {
    int g = blockIdx.x;
    int grp = threadIdx.x >> 4;
    int lane = threadIdx.x & 15;
    int beg = starts[g], end = starts[g + 1];
    float s[8] = {};
    for (int n = beg + grp; n < end; n += 16) {
        h8 v = x8[(size_t)n * 16 + lane];
#pragma unroll
        for (int i = 0; i < 8; ++i) s[i] += (float)v[i];
    }
    __shared__ float red[16][128];
#pragma unroll
    for (int i = 0; i < 8; ++i) red[grp][lane * 8 + i] = s[i];
    __syncthreads();
    if (threadIdx.x < 128) {
        int ch = threadIdx.x;
        float t = 0.f;
#pragma unroll
        for (int gg = 0; gg < 16; ++gg) t += red[gg][ch];
        float cnt = (float)(end - beg);
        pooled[g * D + ch] = fmaf(a[ch], t, cnt * c[ch]);
    }
}

// dense + relu; optional BN applied to the staged input row (head BN fold)
template <int K, bool BN>
__global__ __launch_bounds__(256) void k_dense(const float* __restrict__ in,
                                               const float* __restrict__ W,
                                               const float* __restrict__ b,
                                               const float* __restrict__ a,
                                               const float* __restrict__ c,
                                               float* __restrict__ out) {
    __shared__ float inl[K];
    int row = blockIdx.x;
    for (int k = threadIdx.x; k < K; k += 256) {
        float v = in[row * K + k];
        if (BN) v = fmaf(v, a[k], c[k]);
        inl[k] = v;
    }
    __syncthreads();
    int j = threadIdx.x;
    float acc = b[j];
#pragma unroll
    for (int k = 0; k < K; ++k) acc = fmaf(inl[k], W[k * 256 + j], acc);
    out[row * 256 + j] = fmaxf(acc, 0.0f);
}

__global__ void k_head_stats(const float* __restrict__ x, float* __restrict__ sums,
                             float* __restrict__ sumsq, int rows) {
    int c = threadIdx.x;
    float s = 0.f, s2 = 0.f;
    int r0 = blockIdx.x * 8;
    int r1 = min(r0 + 8, rows);
    for (int r = r0; r < r1; ++r) {
        float v = x[r * DH + c];
        s += v;
        s2 = fmaf(v, v, s2);
    }
    atomicAdd(&sums[c], s);
    atomicAdd(&sumsq[c], s2);
}

// final dot with h1's BN applied in-register
__global__ void k_final(const float* __restrict__ h, const float* __restrict__ a,
                        const float* __restrict__ c, const float* __restrict__ Wout,
                        const float* __restrict__ bout, float* __restrict__ out) {
    int g = blockIdx.x * 4 + (threadIdx.x >> 6);
    int lane = threadIdx.x & 63;
    float4 v = ((const float4*)(h + g * DH))[lane];
    float4 av = ((const float4*)a)[lane];
    float4 cv = ((const float4*)c)[lane];
    float4 w = ((const float4*)Wout)[lane];
    v.x = fmaf(v.x, av.x, cv.x);
    v.y = fmaf(v.y, av.y, cv.y);
    v.z = fmaf(v.z, av.z, cv.z);
    v.w = fmaf(v.w, av.w, cv.w);
    float acc = v.x * w.x + v.y * w.y + v.z * w.z + v.w * w.w;
#pragma unroll
    for (int off = 32; off; off >>= 1) acc += __shfl_down(acc, off, 64);
    if (lane == 0) out[g] = acc + bout[0];
}

// ---------------- launch ----------------

extern "C" void kernel_launch(void* const* d_in, const int* in_sizes, int n_in,
                              void* d_out, int out_size, void* d_ws, size_t ws_size,
                              hipStream_t stream) {
    const float* x = (const float*)d_in[0];
    const int* ei = (const int*)d_in[1];
    const int* batch = (const int*)d_in[2];
    const float* Wc = (const float*)d_in[3];
    const float* bc = (const float*)d_in[4];
    const float* gc = (const float*)d_in[5];
    const float* bec = (const float*)d_in[6];
    const float* Wh0 = (const float*)d_in[7];
    const float* bh0 = (const float*)d_in[8];
    const float* gh0 = (const float*)d_in[9];
    const float* beh0 = (const float*)d_in[10];
    const float* Wh1 = (const float*)d_in[11];
    const float* bh1 = (const float*)d_in[12];
    const float* gh1 = (const float*)d_in[13];
    const float* beh1 = (const float*)d_in[14];
    const float* Wout = (const float*)d_in[15];
    const float* bout = (const float*)d_in[16];
    float* out = (float*)d_out;

    const int* src = ei;
    const int* dst = ei + N_EDGES;

    char* base = (char*)d_ws;
    size_t woff = 0;
    auto alloc = [&](size_t bytes) -> char* {
        char* p = base + woff;
        woff = (woff + bytes + 255) & ~(size_t)255;
        return p;
    };
    _Float16* bufY = (_Float16*)alloc(sizeof(_Float16) * (size_t)N_NODES * D);
    _Float16* bufA = (_Float16*)alloc(sizeof(_Float16) * (size_t)N_NODES * D);
    float* dinv = (float*)alloc(sizeof(float) * N_NODES);
    int* csr = (int*)alloc(sizeof(int) * N_EDGES);
    unsigned* staging = (unsigned*)alloc(sizeof(unsigned) * 8 * PCAP);
    unsigned* stag2 = (unsigned*)alloc(sizeof(unsigned) * 512 * SBCAP);
    // single zeroed region: pcur(64) + pcur2(512) + part[3](3*32*256) + stats[2](2*512)
    size_t zero_bytes = sizeof(int) * (64 + 512) + sizeof(float) * (3 * 32 * 256 + 2 * 512);
    char* zero_base = alloc(zero_bytes);
    int* pcur = (int*)zero_base;
    int* pcur2 = pcur + 64;
    float* part = (float*)(pcur2 + 512);   // 3 layer-indexed buffers
    float* stats0 = part + 3 * 32 * 256;   // h0 sums+sumsq
    float* stats1 = stats0 + 512;          // h1 sums+sumsq
    int* offs = (int*)alloc(sizeof(int) * (N_NODES + 1));
    int* sbbase = (int*)alloc(sizeof(int) * 512);
    float* avec = (float*)alloc(sizeof(float) * 256);
    float* cvec = (float*)alloc(sizeof(float) * 256);
    _Float16* WT = (_Float16*)alloc(sizeof(_Float16) * D * D);
    float* rvec = (float*)alloc(sizeof(float) * 128);
    int* starts = (int*)alloc(sizeof(int) * (N_GRAPHS + 1));
    float* pooled = (float*)alloc(sizeof(float) * N_GRAPHS * D);
    float* h0 = (float*)alloc(sizeof(float) * N_GRAPHS * DH);
    float* h1 = (float*)alloc(sizeof(float) * N_GRAPHS * DH);

    hipMemsetAsync(zero_base, 0, zero_bytes, stream);

    int nbl = (N_NODES + 255) / 256;
    int split_grid = (N_EDGES + FCHUNK - 1) / FCHUNK;
    int split2_grid = ((PCAP + CH2 - 1) / CH2) * 8;
    k_split<<<split_grid, 256, 0, stream>>>(src, dst, pcur, staging);
    k_split2<<<split2_grid, 256, 0, stream>>>(staging, pcur, pcur2, stag2);
    k_sbscan<<<1, 512, 0, stream>>>(pcur2, sbbase, offs);
    k_sort3<<<512, 256, 0, stream>>>(stag2, pcur2, sbbase, offs, dinv, csr);

    int gemm_grid = (N_NODES + 63) / 64;
    for (int layer = 0; layer < 3; ++layer) {
        const float* ppart = part + (size_t)(layer - 1) * 32 * 256;  // unused if layer==0
        k_fold<<<65, 256, 0, stream>>>(Wc + layer * D * D, layer ? ppart : part,
                                       gc + (layer - 1) * D, bec + (layer - 1) * D,
                                       layer > 0, WT, rvec);
        if (layer == 0)
            k_gemm<true><<<gemm_grid, 256, 0, stream>>>(x, WT, rvec, dinv, bufY, N_NODES);
        else
            k_gemm<false><<<gemm_grid, 256, 0, stream>>>(bufA, WT, rvec, dinv, bufY, N_NODES);
        k_aggregate<<<N_NODES / 16, 256, 0, stream>>>(
            (const h8*)bufY, offs, csr, dinv, bc + layer * D, (h8*)bufA,
            part + (size_t)layer * 32 * 256);
    }

    // layer-3 BN coeffs (folded into pooling)
    k_bn_coeffs<<<1, 128, 0, stream>>>(part + 2 * 32 * 256, 32, 256, 128,
                                       gc + 2 * D, bec + 2 * D, avec, cvec,
                                       1.0f / N_NODES);
    k_starts<<<nbl, 256, 0, stream>>>(batch, starts);
    k_pool<<<N_GRAPHS, 256, 0, stream>>>((const h8*)bufA, starts, avec, cvec, pooled);

    k_dense<128, false><<<N_GRAPHS, 256, 0, stream>>>(pooled, Wh0, bh0, nullptr,
                                                      nullptr, h0);
    k_head_stats<<<64, 256, 0, stream>>>(h0, stats0, stats0 + 256, N_GRAPHS);
    k_bn_coeffs<<<1, 256, 0, stream>>>(stats0, 1, 512, 256, gh0, beh0, avec, cvec,
                                       1.0f / N_GRAPHS);
    k_dense<256, true><<<N_GRAPHS, 256, 0, stream>>>(h0, Wh1, bh1, avec, cvec, h1);
    k_head_stats<<<64, 256, 0, stream>>>(h1, stats1, stats1 + 256, N_GRAPHS);
    k_bn_coeffs<<<1, 256, 0, stream>>>(stats1, 1, 512, 256, gh1, beh1, avec, cvec,
                                       1.0f / N_GRAPHS);
    k_final<<<N_GRAPHS / 4, 256, 0, stream>>>(h1, avec, cvec, Wout, bout, out);
}